// Round 5
// baseline (161.584 us; speedup 1.0000x reference)
//
#include <hip/hip_runtime.h>

// MoE all-experts dense MLP, fused bf16-MFMA kernel.
// E=8, D_IN=128, D_HID=256, D_OUT=128, B=65536. Out f32 [B,128].
// Structure: block = 2 waves x same 64 batch rows, c-split (each wave owns 32
// of the 64 hidden cols per chunk); BM=64, grid=1024 -> 4 blocks/CU, 8 waves/CU
// (2/SIMD). W1 chunk records (swizzled bf16 + b1) LDS-double-buffered; W2 read
// global-direct from a coalesced per-fragment packing. Partial out summed over
// c-halves, merged via LDS at epilogue.

#define E_    8
#define DIN_  128
#define DH_   256
#define DOUT_ 128
#define BM_   64
#define NCHUNK 32
#define REC1  18432   // 16K W1c (swizzled) + 2K b1 rows (64 x 32B)

typedef __attribute__((ext_vector_type(8))) short bf16x8;
typedef __attribute__((ext_vector_type(16))) float f32x16;
typedef __attribute__((ext_vector_type(2))) unsigned int uint2v;

__device__ __forceinline__ unsigned short f2bf(float f) {
  union { float f; unsigned int u; } v; v.f = f;
  unsigned int u = v.u;
  u += 0x7fffu + ((u >> 16) & 1u);
  return (unsigned short)(u >> 16);
}

__device__ __forceinline__ unsigned int cvt_pk_bf16(float lo, float hi) {
  unsigned int r;
  asm("v_cvt_pk_bf16_f32 %0, %1, %2" : "=v"(r) : "v"(lo), "v"(hi));
  return r;
}

__device__ __forceinline__ bf16x8 pack4(unsigned int a, unsigned int b,
                                        unsigned int c, unsigned int d) {
  union { unsigned int u[4]; bf16x8 v; } t;
  t.u[0] = a; t.u[1] = b; t.u[2] = c; t.u[3] = d;
  return t.v;
}

__device__ __forceinline__ void gload_lds16(const void* g, void* l) {
  __builtin_amdgcn_global_load_lds(
      (const __attribute__((address_space(1))) unsigned int*)g,
      (__attribute__((address_space(3))) unsigned int*)l, 16, 0, 0);
}

// ---------------- prep 1: W1 chunk records ----------------
// Record t (e=t>>2, hc=t&3), REC1 bytes:
//  [0,16K):   W1c rows c=0..63 x 256B(k): rec[c*256+u] = bf16bytes[c][u^((c&7)<<4)]
//  [16K,18K): b1 rows c=0..63 x 32B: word0 = bf16(b1[..]), rest zero
__global__ __launch_bounds__(256) void prep_w1(
    const float* __restrict__ W1, const float* __restrict__ b1,
    unsigned char* __restrict__ W1r)
{
  __shared__ float T[8192];
  const int t = blockIdx.x;
  const int e = t >> 2, hc = t & 3;
  const int tid = threadIdx.x;
  unsigned char* rec = W1r + (size_t)t * REC1;

  // T[k*64+c] = W1[e][k][hc*64+c]   (W1: [E][DIN][DH])
  #pragma unroll
  for (int i = 0; i < 32; ++i) {
    int idx = i * 256 + tid;
    int k = idx >> 6, c = idx & 63;
    T[idx] = W1[((size_t)(e * DIN_ + k)) * DH_ + hc * 64 + c];
  }
  __syncthreads();
  #pragma unroll
  for (int j = 0; j < 16; ++j) {
    int widx = j * 256 + tid;              // 4096 words
    int c = widx >> 6, uw = (widx & 63) * 4;
    int up = uw ^ ((c & 7) << 4);
    int k0 = up >> 1;                      // even
    unsigned int val = (unsigned int)f2bf(T[k0 * 64 + c]) |
                       ((unsigned int)f2bf(T[(k0 + 1) * 64 + c]) << 16);
    *(unsigned int*)(rec + c * 256 + uw) = val;
  }
  if (tid < 64) {
    *(unsigned int*)(rec + 16384 + tid * 32) =
        (unsigned int)f2bf(b1[e * DH_ + hc * 64 + tid]);
    #pragma unroll
    for (int p = 1; p < 8; ++p)
      *(unsigned int*)(rec + 16384 + tid * 32 + p * 4) = 0u;
  }
}

// ---------------- prep 2: W2 coalesced fragment packing ----------------
// W2p[t][wh][k2][nf][lane] = 16B: lane=(l32,hi): n=nf*32+l32,
// c = hc*64 + wh*32 + k2*16 + hi*8 + j (j=0..7), from W2[E][DH][DOUT] f32.
__global__ __launch_bounds__(256) void prep_w2p(
    const float* __restrict__ W2, unsigned int* __restrict__ W2p)
{
  const int t = blockIdx.x;
  const int e = t >> 2, hc = t & 3;
  const int tid = threadIdx.x;
  unsigned int* outw = W2p + (size_t)t * 4096;
  #pragma unroll
  for (int j = 0; j < 16; ++j) {
    int w = j * 256 + tid;                 // 0..4095
    int wh = w >> 11, k2 = (w >> 10) & 1, nf = (w >> 8) & 3;
    int lane = (w >> 2) & 63, pr = w & 3;
    int hi = lane >> 5, l32 = lane & 31;
    int n = nf * 32 + l32;
    int c = hc * 64 + wh * 32 + k2 * 16 + hi * 8 + pr * 2;
    unsigned int val =
        (unsigned int)f2bf(W2[((size_t)(e * DH_ + c)) * DOUT_ + n]) |
        ((unsigned int)f2bf(W2[((size_t)(e * DH_ + c + 1)) * DOUT_ + n]) << 16);
    outw[w] = val;
  }
}

// ---------------- main fused kernel ----------------
__global__ __launch_bounds__(128, 2) void moe_main(
    const float* __restrict__ x, const float* __restrict__ wts,
    const float* __restrict__ b2, const unsigned char* __restrict__ W1r,
    const unsigned char* __restrict__ W2p, float* __restrict__ out)
{
  __shared__ __align__(16) unsigned char L[2][REC1];   // 36.9 KB

  const int tid  = threadIdx.x;
  const int lane = tid & 63;
  const int wv   = tid >> 6;        // 0..1 : c-half owner
  const int l32  = lane & 31;
  const int hi   = lane >> 5;
  const int swz  = (l32 & 7) << 4;
  const long bm  = (long)blockIdx.x * BM_;

  auto stage = [&](int t, unsigned char* dst) {
    const unsigned char* src = W1r + (size_t)t * REC1;
    #pragma unroll
    for (int r = 0; r < 9; ++r)
      gload_lds16(src + (r * 128 + tid) * 16, dst + r * 2048 + wv * 1024);
  };

  stage(0, L[0]);

  // precomputed LDS offsets: wave reads its own 32 c-rows (c = wv*32 + l32)
  int p1o[8];
  #pragma unroll
  for (int ks = 0; ks < 8; ++ks)
    p1o[ks] = (wv * 32 + l32) * 256 + ((ks * 32 + hi * 16) ^ swz);
  const int bo = 16384 + (wv * 32 + l32) * 32 + hi * 16;

  const bf16x8 ones = pack4(hi ? 0u : 0x3F80u, 0u, 0u, 0u);

  // x fragments: xf[mt][ks], col=m=l32 (rows bm+mt*32+l32), k = ks*16+hi*8+j
  bf16x8 xf[2][8];
  #pragma unroll
  for (int mt = 0; mt < 2; ++mt) {
    const float* xr0 = x + (bm + mt * 32 + l32) * DIN_;
    #pragma unroll
    for (int ks = 0; ks < 8; ++ks) {
      const float* xr = xr0 + ks * 16 + hi * 8;
      float4 a = *(const float4*)xr;
      float4 b = *(const float4*)(xr + 4);
      xf[mt][ks] = pack4(cvt_pk_bf16(a.x, a.y), cvt_pk_bf16(a.z, a.w),
                         cvt_pk_bf16(b.x, b.y), cvt_pk_bf16(b.z, b.w));
    }
  }

  const float* wp0 = wts + (bm + l32) * E_;        // row mt=0
  const float* wp1 = wts + (bm + 32 + l32) * E_;   // row mt=1

  f32x16 oacc[2][4];   // [mt][nf]; partial over this wave's c-half
  #pragma unroll
  for (int mt = 0; mt < 2; ++mt)
    #pragma unroll
    for (int nf = 0; nf < 4; ++nf) oacc[mt][nf] = 0.0f;

  for (int t = 0; t < NCHUNK; ++t) {
    const int e = t >> 2;
    __syncthreads();                       // L[t&1] staged; L[(t+1)&1] free
    if (t + 1 < NCHUNK) stage(t + 1, L[(t + 1) & 1]);
    const unsigned char* Lb = L[t & 1];

    // W2 fragments for this wave's c-half: coalesced 16B/lane, L1/L2-hot.
    bf16x8 w2f[8];     // index k2*4+nf
    {
      const unsigned char* wb = W2p + (size_t)t * 16384 + wv * 8192 + lane * 16;
      #pragma unroll
      for (int i = 0; i < 8; ++i)
        w2f[i] = *(const bf16x8*)(wb + i * 1024);
    }
    const float wA = wp0[e], wB = wp1[e];
    bf16x8 bfr = *(const bf16x8*)(Lb + bo);

    // ---- phase 1: H-half^T[c][m], c = wv*32 + 0..31, K=128
    f32x16 h0 = 0.0f, h1 = 0.0f;           // [mt]
    __builtin_amdgcn_s_setprio(1);
    #pragma unroll
    for (int ks = 0; ks < 8; ++ks) {
      bf16x8 a = *(const bf16x8*)(Lb + p1o[ks]);
      h0 = __builtin_amdgcn_mfma_f32_32x32x16_bf16(a, xf[0][ks], h0, 0, 0, 0);
      h1 = __builtin_amdgcn_mfma_f32_32x32x16_bf16(a, xf[1][ks], h1, 0, 0, 0);
    }
    h0 = __builtin_amdgcn_mfma_f32_32x32x16_bf16(bfr, ones, h0, 0, 0, 0);
    h1 = __builtin_amdgcn_mfma_f32_32x32x16_bf16(bfr, ones, h1, 0, 0, 0);
    __builtin_amdgcn_s_setprio(0);

    // ---- relu + fold w; cvt_pk + permlane32_swap -> phase-2 A-frags (T12)
    bf16x8 hfr0[2], hfr1[2];
    #pragma unroll
    for (int mt = 0; mt < 2; ++mt) {
      const f32x16& hh = mt ? h1 : h0;
      const float w = mt ? wB : wA;
      unsigned int u[8];
      #pragma unroll
      for (int p = 0; p < 8; ++p) {
        float a = fmaxf(hh[2 * p],     0.0f) * w;
        float b = fmaxf(hh[2 * p + 1], 0.0f) * w;
        u[p] = cvt_pk_bf16(a, b);
      }
      uint2v s02 = __builtin_amdgcn_permlane32_swap(u[0], u[2], false, false);
      uint2v s13 = __builtin_amdgcn_permlane32_swap(u[1], u[3], false, false);
      uint2v s46 = __builtin_amdgcn_permlane32_swap(u[4], u[6], false, false);
      uint2v s57 = __builtin_amdgcn_permlane32_swap(u[5], u[7], false, false);
      bf16x8 f0 = pack4(s02[0], s13[0], s02[1], s13[1]);
      bf16x8 f1 = pack4(s46[0], s57[0], s46[1], s57[1]);
      if (mt) { hfr1[0] = f0; hfr1[1] = f1; }
      else    { hfr0[0] = f0; hfr0[1] = f1; }
    }

    // ---- phase 2: partial out += H-half * W2 (k over this c-half)
    __builtin_amdgcn_s_setprio(1);
    #pragma unroll
    for (int k2 = 0; k2 < 2; ++k2) {
      #pragma unroll
      for (int nf = 0; nf < 4; ++nf) {
        bf16x8 b = w2f[k2 * 4 + nf];
        oacc[0][nf] = __builtin_amdgcn_mfma_f32_32x32x16_bf16(hfr0[k2], b, oacc[0][nf], 0, 0, 0);
        oacc[1][nf] = __builtin_amdgcn_mfma_f32_32x32x16_bf16(hfr1[k2], b, oacc[1][nf], 0, 0, 0);
      }
    }
    __builtin_amdgcn_s_setprio(0);
  }

  // ---- epilogue: merge c-half partials via LDS, fold b2, store (wave 0)
  __syncthreads();                         // all chunk reads done; L reusable
  float* X = (float*)&L[0][0];             // 32 KB scratch
  if (wv == 1) {
    #pragma unroll
    for (int mt = 0; mt < 2; ++mt)
      #pragma unroll
      for (int nf = 0; nf < 4; ++nf)
        #pragma unroll
        for (int r = 0; r < 16; ++r) {
          const int mloc = (r & 3) + 8 * (r >> 2) + 4 * hi;
          X[(mt * 32 + mloc) * DOUT_ + nf * 32 + l32] = oacc[mt][nf][r];
        }
  }
  __syncthreads();
  if (wv == 0) {
    #pragma unroll
    for (int mt = 0; mt < 2; ++mt)
      #pragma unroll
      for (int nf = 0; nf < 4; ++nf)
        #pragma unroll
        for (int r = 0; r < 16; ++r) {
          const int mloc = (r & 3) + 8 * (r >> 2) + 4 * hi;
          oacc[mt][nf][r] += X[(mt * 32 + mloc) * DOUT_ + nf * 32 + l32];
        }

    // fold Sigma_e w[m][e]*b2[e][n] via one rank-8 MFMA per frag
    const unsigned int z = 0;
    float wv0[8], wv1[8];
    {
      float4 a = *(const float4*)wp0; float4 b = *(const float4*)(wp0 + 4);
      wv0[0]=a.x; wv0[1]=a.y; wv0[2]=a.z; wv0[3]=a.w;
      wv0[4]=b.x; wv0[5]=b.y; wv0[6]=b.z; wv0[7]=b.w;
      float4 c = *(const float4*)wp1; float4 d = *(const float4*)(wp1 + 4);
      wv1[0]=c.x; wv1[1]=c.y; wv1[2]=c.z; wv1[3]=c.w;
      wv1[4]=d.x; wv1[5]=d.y; wv1[6]=d.z; wv1[7]=d.w;
    }
    bf16x8 wfrag[2];
    wfrag[0] = pack4(hi ? z : cvt_pk_bf16(wv0[0], wv0[1]),
                     hi ? z : cvt_pk_bf16(wv0[2], wv0[3]),
                     hi ? z : cvt_pk_bf16(wv0[4], wv0[5]),
                     hi ? z : cvt_pk_bf16(wv0[6], wv0[7]));
    wfrag[1] = pack4(hi ? z : cvt_pk_bf16(wv1[0], wv1[1]),
                     hi ? z : cvt_pk_bf16(wv1[2], wv1[3]),
                     hi ? z : cvt_pk_bf16(wv1[4], wv1[5]),
                     hi ? z : cvt_pk_bf16(wv1[6], wv1[7]));
    #pragma unroll
    for (int nf = 0; nf < 4; ++nf) {
      const float* bp = b2 + nf * 32 + l32;
      bf16x8 bfrag = pack4(
          hi ? z : cvt_pk_bf16(bp[0 * DOUT_], bp[1 * DOUT_]),
          hi ? z : cvt_pk_bf16(bp[2 * DOUT_], bp[3 * DOUT_]),
          hi ? z : cvt_pk_bf16(bp[4 * DOUT_], bp[5 * DOUT_]),
          hi ? z : cvt_pk_bf16(bp[6 * DOUT_], bp[7 * DOUT_]));
      oacc[0][nf] = __builtin_amdgcn_mfma_f32_32x32x16_bf16(wfrag[0], bfrag, oacc[0][nf], 0, 0, 0);
      oacc[1][nf] = __builtin_amdgcn_mfma_f32_32x32x16_bf16(wfrag[1], bfrag, oacc[1][nf], 0, 0, 0);
    }

    #pragma unroll
    for (int mt = 0; mt < 2; ++mt)
      #pragma unroll
      for (int nf = 0; nf < 4; ++nf)
        #pragma unroll
        for (int r = 0; r < 16; ++r) {
          const int mloc = (r & 3) + 8 * (r >> 2) + 4 * hi;
          out[(bm + mt * 32 + mloc) * DOUT_ + nf * 32 + l32] = oacc[mt][nf][r];
        }
  }
}

extern "C" void kernel_launch(void* const* d_in, const int* in_sizes, int n_in,
                              void* d_out, int out_size, void* d_ws, size_t ws_size,
                              hipStream_t stream) {
  const float* x   = (const float*)d_in[0];
  const float* wts = (const float*)d_in[1];
  const float* W1  = (const float*)d_in[2];
  const float* b1  = (const float*)d_in[3];
  const float* W2  = (const float*)d_in[4];
  const float* b2  = (const float*)d_in[5];
  float* out = (float*)d_out;

  unsigned char* W1r = (unsigned char*)d_ws;               // 32*18432 = 576 KB
  unsigned char* W2p = W1r + (size_t)NCHUNK * REC1;        // 32*16384 = 512 KB

  prep_w1<<<32, 256, 0, stream>>>(W1, b1, W1r);
  prep_w2p<<<32, 256, 0, stream>>>(W2, (unsigned int*)W2p);
  moe_main<<<65536 / BM_, 128, 0, stream>>>(x, wts, b2, W1r, W2p, out);
}

// Round 6
// 100.462 us; speedup vs baseline: 1.6084x; 1.6084x over previous
//
#include <hip/hip_runtime.h>

// MoE all-experts dense MLP, fused bf16-MFMA kernel.
// E=8, D_IN=128, D_HID=256, D_OUT=128, B=65536. Out f32 [B,128].
// Block = 256 thr / 4 waves over BM=128 rows: wave = (mh,ch); mh picks 64 rows
// (M=64/wave via xf[2]); ch picks 32 of the 64 hidden cols per chunk (c-split,
// partial out merged via LDS at epilogue). Chunk record (W1 swz + W2 swz + b1)
// double-buffered in LDS; grid 512 -> 2 blocks/CU, 8 waves/CU (2/SIMD).

#define E_    8
#define DIN_  128
#define DH_   256
#define DOUT_ 128
#define BM_   128
#define NCHUNK 32
#define RECSZ 34816   // 16K W1c + 16K W2c + 2K b1

typedef __attribute__((ext_vector_type(8))) short bf16x8;
typedef __attribute__((ext_vector_type(16))) float f32x16;
typedef __attribute__((ext_vector_type(2))) unsigned int uint2v;

__device__ __forceinline__ unsigned short f2bf(float f) {
  union { float f; unsigned int u; } v; v.f = f;
  unsigned int u = v.u;
  u += 0x7fffu + ((u >> 16) & 1u);
  return (unsigned short)(u >> 16);
}

__device__ __forceinline__ unsigned int cvt_pk_bf16(float lo, float hi) {
  unsigned int r;
  asm("v_cvt_pk_bf16_f32 %0, %1, %2" : "=v"(r) : "v"(lo), "v"(hi));
  return r;
}

__device__ __forceinline__ bf16x8 pack4(unsigned int a, unsigned int b,
                                        unsigned int c, unsigned int d) {
  union { unsigned int u[4]; bf16x8 v; } t;
  t.u[0] = a; t.u[1] = b; t.u[2] = c; t.u[3] = d;
  return t.v;
}

__device__ __forceinline__ void gload_lds16(const void* g, void* l) {
  __builtin_amdgcn_global_load_lds(
      (const __attribute__((address_space(1))) unsigned int*)g,
      (__attribute__((address_space(3))) unsigned int*)l, 16, 0, 0);
}

// ---------------- prep: build Wall[32][RECSZ] (verified in R4) ----------------
// Record t (e=t>>2, hc=t&3):
//  [0,16K):   W1c rows c=0..63 x 256B(k): rec[c*256+u] = bf16bytes[c][u^((c&7)<<4)]
//  [16K,32K): W2c rows n=0..127 x 128B(c): rec[16K+n*128+u] = bf16bytes[n][u^((n&7)<<4)]
//  [32K,34K): b1 rows c=0..63 x 32B: word0 = bf16(b1), rest zero
__global__ __launch_bounds__(256) void prep_pack(
    const float* __restrict__ W1, const float* __restrict__ W2,
    const float* __restrict__ b1, unsigned char* __restrict__ Wall)
{
  __shared__ float T[8192];
  const int bid = blockIdx.x;
  const int t = bid >> 1, region = bid & 1;
  const int e = t >> 2, hc = t & 3;
  const int tid = threadIdx.x;
  unsigned char* rec = Wall + (size_t)t * RECSZ;

  if (region == 0) {
    #pragma unroll
    for (int i = 0; i < 32; ++i) {
      int idx = i * 256 + tid;
      int k = idx >> 6, c = idx & 63;
      T[idx] = W1[((size_t)(e * DIN_ + k)) * DH_ + hc * 64 + c];
    }
    __syncthreads();
    #pragma unroll
    for (int j = 0; j < 16; ++j) {
      int widx = j * 256 + tid;
      int c = widx >> 6, uw = (widx & 63) * 4;
      int up = uw ^ ((c & 7) << 4);
      int k0 = up >> 1;
      unsigned int val = (unsigned int)f2bf(T[k0 * 64 + c]) |
                         ((unsigned int)f2bf(T[(k0 + 1) * 64 + c]) << 16);
      *(unsigned int*)(rec + c * 256 + uw) = val;
    }
    if (tid < 64) {
      *(unsigned int*)(rec + 32768 + tid * 32) =
          (unsigned int)f2bf(b1[e * DH_ + hc * 64 + tid]);
      #pragma unroll
      for (int p = 1; p < 8; ++p)
        *(unsigned int*)(rec + 32768 + tid * 32 + p * 4) = 0u;
    }
  } else {
    #pragma unroll
    for (int i = 0; i < 32; ++i) {
      int idx = i * 256 + tid;
      int h = idx >> 7, n = idx & 127;
      T[idx] = W2[((size_t)(e * DH_ + hc * 64 + h)) * DOUT_ + n];
    }
    __syncthreads();
    #pragma unroll
    for (int j = 0; j < 16; ++j) {
      int widx = j * 256 + tid;
      int n = widx >> 5, uw = (widx & 31) * 4;
      int up = uw ^ ((n & 7) << 4);
      int h0 = up >> 1;
      unsigned int val = (unsigned int)f2bf(T[h0 * 128 + n]) |
                         ((unsigned int)f2bf(T[(h0 + 1) * 128 + n]) << 16);
      *(unsigned int*)(rec + 16384 + n * 128 + uw) = val;
    }
  }
}

// ---------------- main fused kernel ----------------
__global__ __launch_bounds__(256, 2) void moe_main(
    const float* __restrict__ x, const float* __restrict__ wts,
    const float* __restrict__ b2, const unsigned char* __restrict__ Wall,
    float* __restrict__ out)
{
  __shared__ __align__(16) unsigned char L[2][RECSZ];   // 68 KB dbuf

  const int tid  = threadIdx.x;
  const int lane = tid & 63;
  const int wv   = tid >> 6;        // 0..3
  const int mh   = wv >> 1;         // 64-row half
  const int ch   = wv & 1;          // 32-col c-half of the chunk
  const int l32  = lane & 31;
  const int hi   = lane >> 5;
  const int swz  = (l32 & 7) << 4;
  const long bm  = (long)blockIdx.x * BM_;
  const long r0  = bm + mh * 64 + l32;   // mt=0 row for this lane; mt=1 is +32

  auto stage = [&](int t, unsigned char* dst) {
    const unsigned char* src = Wall + (size_t)t * RECSZ;
    #pragma unroll
    for (int r = 0; r < 8; ++r)
      gload_lds16(src + (r * 256 + tid) * 16, dst + r * 4096 + wv * 1024);
    if (wv < 2)
      gload_lds16(src + 32768 + tid * 16, dst + 32768 + wv * 1024);
  };

  stage(0, L[0]);

  // precomputed LDS read offsets
  int p1o[8];
  #pragma unroll
  for (int ks = 0; ks < 8; ++ks)
    p1o[ks] = (ch * 32 + l32) * 256 + ((ks * 32 + hi * 16) ^ swz);
  int p2o[2];
  #pragma unroll
  for (int k2 = 0; k2 < 2; ++k2)
    p2o[k2] = 16384 + l32 * 128 + ((ch * 64 + k2 * 32 + hi * 16) ^ swz);
  const int bo = 32768 + (ch * 32 + l32) * 32 + hi * 16;

  const bf16x8 ones = pack4(hi ? 0u : 0x3F80u, 0u, 0u, 0u);

  // x fragments: xf[mt][ks], B-frag col=m=l32, k = ks*16 + hi*8 + j
  bf16x8 xf[2][8];
  #pragma unroll
  for (int mt = 0; mt < 2; ++mt) {
    const float* xr0 = x + (r0 + mt * 32) * DIN_;
    #pragma unroll
    for (int ks = 0; ks < 8; ++ks) {
      const float* xr = xr0 + ks * 16 + hi * 8;
      float4 a = *(const float4*)xr;
      float4 b = *(const float4*)(xr + 4);
      xf[mt][ks] = pack4(cvt_pk_bf16(a.x, a.y), cvt_pk_bf16(a.z, a.w),
                         cvt_pk_bf16(b.x, b.y), cvt_pk_bf16(b.z, b.w));
    }
  }

  const float* wp0 = wts + r0 * E_;          // expert weights, row mt=0
  const float* wp1 = wts + (r0 + 32) * E_;   // row mt=1

  f32x16 oacc[2][4];   // [mt][nf]; partial over this wave's c-half
  #pragma unroll
  for (int mt = 0; mt < 2; ++mt)
    #pragma unroll
    for (int nf = 0; nf < 4; ++nf) oacc[mt][nf] = 0.0f;

  for (int t = 0; t < NCHUNK; ++t) {
    const int e = t >> 2;
    __syncthreads();                       // L[t&1] staged; L[(t+1)&1] free
    if (t + 1 < NCHUNK) stage(t + 1, L[(t + 1) & 1]);
    const unsigned char* Lb = L[t & 1];

    const float wA = wp0[e], wB = wp1[e];
    bf16x8 bfr = *(const bf16x8*)(Lb + bo);

    // ---- phase 1: H-half^T[c][m], c = ch*32 + l32-rows, K=128, M=64 via mt
    f32x16 h0 = 0.0f, h1 = 0.0f;
    __builtin_amdgcn_s_setprio(1);
    #pragma unroll
    for (int ks = 0; ks < 8; ++ks) {
      bf16x8 a = *(const bf16x8*)(Lb + p1o[ks]);
      h0 = __builtin_amdgcn_mfma_f32_32x32x16_bf16(a, xf[0][ks], h0, 0, 0, 0);
      h1 = __builtin_amdgcn_mfma_f32_32x32x16_bf16(a, xf[1][ks], h1, 0, 0, 0);
    }
    h0 = __builtin_amdgcn_mfma_f32_32x32x16_bf16(bfr, ones, h0, 0, 0, 0);
    h1 = __builtin_amdgcn_mfma_f32_32x32x16_bf16(bfr, ones, h1, 0, 0, 0);
    __builtin_amdgcn_s_setprio(0);

    // ---- relu + fold w; cvt_pk + permlane32_swap -> phase-2 A-frags (T12)
    bf16x8 hfr0[2], hfr1[2];
    #pragma unroll
    for (int mt = 0; mt < 2; ++mt) {
      const f32x16& hh = mt ? h1 : h0;
      const float w = mt ? wB : wA;
      unsigned int u[8];
      #pragma unroll
      for (int p = 0; p < 8; ++p) {
        float a = fmaxf(hh[2 * p],     0.0f) * w;
        float b = fmaxf(hh[2 * p + 1], 0.0f) * w;
        u[p] = cvt_pk_bf16(a, b);
      }
      uint2v s02 = __builtin_amdgcn_permlane32_swap(u[0], u[2], false, false);
      uint2v s13 = __builtin_amdgcn_permlane32_swap(u[1], u[3], false, false);
      uint2v s46 = __builtin_amdgcn_permlane32_swap(u[4], u[6], false, false);
      uint2v s57 = __builtin_amdgcn_permlane32_swap(u[5], u[7], false, false);
      bf16x8 f0 = pack4(s02[0], s13[0], s02[1], s13[1]);
      bf16x8 f1 = pack4(s46[0], s57[0], s46[1], s57[1]);
      if (mt) { hfr1[0] = f0; hfr1[1] = f1; }
      else    { hfr0[0] = f0; hfr0[1] = f1; }
    }

    // ---- phase 2: partial out += H-half * W2 (k over this c-half)
    __builtin_amdgcn_s_setprio(1);
    #pragma unroll
    for (int k2 = 0; k2 < 2; ++k2) {
      #pragma unroll
      for (int nf = 0; nf < 4; ++nf) {
        bf16x8 b = *(const bf16x8*)(Lb + p2o[k2] + nf * 4096);
        oacc[0][nf] = __builtin_amdgcn_mfma_f32_32x32x16_bf16(hfr0[k2], b, oacc[0][nf], 0, 0, 0);
        oacc[1][nf] = __builtin_amdgcn_mfma_f32_32x32x16_bf16(hfr1[k2], b, oacc[1][nf], 0, 0, 0);
      }
    }
    __builtin_amdgcn_s_setprio(0);
  }

  // ---- epilogue: merge c-half partials via LDS, fold b2, store (ch==0)
  __syncthreads();                         // all chunk reads done; L reusable
  float* X = (float*)&L[0][0];             // [2 mh][64 m][128 n] f32 = 64 KB
  if (ch == 1) {
    #pragma unroll
    for (int mt = 0; mt < 2; ++mt)
      #pragma unroll
      for (int nf = 0; nf < 4; ++nf)
        #pragma unroll
        for (int r = 0; r < 16; ++r) {
          const int mloc = (r & 3) + 8 * (r >> 2) + 4 * hi;
          X[(mh * 64 + mt * 32 + mloc) * DOUT_ + nf * 32 + l32] = oacc[mt][nf][r];
        }
  }
  __syncthreads();
  if (ch == 0) {
    #pragma unroll
    for (int mt = 0; mt < 2; ++mt)
      #pragma unroll
      for (int nf = 0; nf < 4; ++nf)
        #pragma unroll
        for (int r = 0; r < 16; ++r) {
          const int mloc = (r & 3) + 8 * (r >> 2) + 4 * hi;
          oacc[mt][nf][r] += X[(mh * 64 + mt * 32 + mloc) * DOUT_ + nf * 32 + l32];
        }

    // fold Sigma_e w[m][e]*b2[e][n] via one rank-8 MFMA per frag (verified R3/R4)
    const unsigned int z = 0;
    float w0v[8], w1v[8];
    {
      float4 a = *(const float4*)wp0; float4 b = *(const float4*)(wp0 + 4);
      w0v[0]=a.x; w0v[1]=a.y; w0v[2]=a.z; w0v[3]=a.w;
      w0v[4]=b.x; w0v[5]=b.y; w0v[6]=b.z; w0v[7]=b.w;
      float4 c = *(const float4*)wp1; float4 d = *(const float4*)(wp1 + 4);
      w1v[0]=c.x; w1v[1]=c.y; w1v[2]=c.z; w1v[3]=c.w;
      w1v[4]=d.x; w1v[5]=d.y; w1v[6]=d.z; w1v[7]=d.w;
    }
    bf16x8 wfrag[2];
    wfrag[0] = pack4(hi ? z : cvt_pk_bf16(w0v[0], w0v[1]),
                     hi ? z : cvt_pk_bf16(w0v[2], w0v[3]),
                     hi ? z : cvt_pk_bf16(w0v[4], w0v[5]),
                     hi ? z : cvt_pk_bf16(w0v[6], w0v[7]));
    wfrag[1] = pack4(hi ? z : cvt_pk_bf16(w1v[0], w1v[1]),
                     hi ? z : cvt_pk_bf16(w1v[2], w1v[3]),
                     hi ? z : cvt_pk_bf16(w1v[4], w1v[5]),
                     hi ? z : cvt_pk_bf16(w1v[6], w1v[7]));
    #pragma unroll
    for (int nf = 0; nf < 4; ++nf) {
      const float* bp = b2 + nf * 32 + l32;
      bf16x8 bfrag = pack4(
          hi ? z : cvt_pk_bf16(bp[0 * DOUT_], bp[1 * DOUT_]),
          hi ? z : cvt_pk_bf16(bp[2 * DOUT_], bp[3 * DOUT_]),
          hi ? z : cvt_pk_bf16(bp[4 * DOUT_], bp[5 * DOUT_]),
          hi ? z : cvt_pk_bf16(bp[6 * DOUT_], bp[7 * DOUT_]));
      oacc[0][nf] = __builtin_amdgcn_mfma_f32_32x32x16_bf16(wfrag[0], bfrag, oacc[0][nf], 0, 0, 0);
      oacc[1][nf] = __builtin_amdgcn_mfma_f32_32x32x16_bf16(wfrag[1], bfrag, oacc[1][nf], 0, 0, 0);
    }

    #pragma unroll
    for (int mt = 0; mt < 2; ++mt)
      #pragma unroll
      for (int nf = 0; nf < 4; ++nf)
        #pragma unroll
        for (int r = 0; r < 16; ++r) {
          const int mloc = (r & 3) + 8 * (r >> 2) + 4 * hi;
          out[(bm + mh * 64 + mt * 32 + mloc) * DOUT_ + nf * 32 + l32] =
              oacc[mt][nf][r];
        }
  }
}

extern "C" void kernel_launch(void* const* d_in, const int* in_sizes, int n_in,
                              void* d_out, int out_size, void* d_ws, size_t ws_size,
                              hipStream_t stream) {
  const float* x   = (const float*)d_in[0];
  const float* wts = (const float*)d_in[1];
  const float* W1  = (const float*)d_in[2];
  const float* b1  = (const float*)d_in[3];
  const float* W2  = (const float*)d_in[4];
  const float* b2  = (const float*)d_in[5];
  float* out = (float*)d_out;

  unsigned char* Wall = (unsigned char*)d_ws;   // 32 * 34816 = 1.06 MB

  prep_pack<<<64, 256, 0, stream>>>(W1, W2, b1, Wall);
  moe_main<<<65536 / BM_, 256, 0, stream>>>(x, wts, b2, Wall, out);
}